// Round 1
// 3080.826 us; speedup vs baseline: 1.0954x; 1.0954x over previous
//
#include <hip/hip_runtime.h>
#include <cstdint>
#include <cstddef>

// ---------- types / helpers ----------
typedef __attribute__((ext_vector_type(8))) short short8;   // 8 x bf16 (4 VGPRs)
typedef __attribute__((ext_vector_type(4))) float floatx4;  // 4 x f32 accum

__device__ __forceinline__ float bf2f(unsigned short u) {
    union { float f; uint32_t i; } v; v.i = ((uint32_t)u) << 16; return v.f;
}
__device__ __forceinline__ unsigned short f2bf(float f) {
    union { float f; uint32_t i; } v; v.f = f;
    uint32_t r = v.i + 0x7FFFu + ((v.i >> 16) & 1u);  // round-nearest-even
    return (unsigned short)(r >> 16);
}

// async global->LDS, 16B per lane. LDS dest must be wave-uniform base;
// HW writes lane l's 16B at base + l*16.
__device__ __forceinline__ void gl_lds16(const unsigned short* g, unsigned short* l) {
    __builtin_amdgcn_global_load_lds(
        (const __attribute__((address_space(1))) unsigned int*)g,
        (__attribute__((address_space(3))) unsigned int*)l,
        16, 0, 0);
}

// bijective XCD-aware block swizzle (m204): contiguous chunk of ids per XCD
__device__ __forceinline__ int xcd_swizzle(int bid, int nwg) {
    const int nx = 8;
    const int q = nwg / nx, r = nwg % nx;
    const int xcd = bid % nx, local = bid / nx;
    return (xcd < r ? xcd * (q + 1) : r * (q + 1) + (xcd - r) * q) + local;
}

// ---------- fused add + RMSNorm -> bf16 ----------
__global__ __launch_bounds__(256)
void add_rmsnorm_kernel(const float* __restrict__ x, const float* __restrict__ res,
                        const float* __restrict__ w, unsigned short* __restrict__ out,
                        int H, float invH)
{
    const size_t row = blockIdx.x;
    const float4* xv = (const float4*)(x + row * (size_t)H);
    const float4* rv = (const float4*)(res + row * (size_t)H);
    const float4* wv = (const float4*)w;
    const int nvec = H >> 2;
    float4 h[8];
    float s = 0.f;
    int cnt = 0;
    for (int idx = threadIdx.x; idx < nvec; idx += 256) {
        float4 a = xv[idx], b = rv[idx];
        float4 hh = make_float4(a.x + b.x, a.y + b.y, a.z + b.z, a.w + b.w);
        h[cnt++] = hh;
        s += hh.x * hh.x + hh.y * hh.y + hh.z * hh.z + hh.w * hh.w;
    }
    __shared__ float red[256];
    red[threadIdx.x] = s;
    __syncthreads();
    for (int off = 128; off > 0; off >>= 1) {
        if (threadIdx.x < off) red[threadIdx.x] += red[threadIdx.x + off];
        __syncthreads();
    }
    const float scale = rsqrtf(red[0] * invH + 1e-5f);
    ushort4* ov = (ushort4*)(out + row * (size_t)H);
    cnt = 0;
    for (int idx = threadIdx.x; idx < nvec; idx += 256) {
        float4 hh = h[cnt++];
        float4 ww = wv[idx];
        ushort4 o;
        o.x = f2bf(hh.x * scale * ww.x);
        o.y = f2bf(hh.y * scale * ww.y);
        o.z = f2bf(hh.z * scale * ww.z);
        o.w = f2bf(hh.w * scale * ww.w);
        ov[idx] = o;
    }
}

// ---------- fp32 [P,Q] -> bf16 [Qld,Pld] transpose+cast, zero-padded ----------
__global__ __launch_bounds__(256)
void transpose_cast(const float* __restrict__ src, unsigned short* __restrict__ dst,
                    int P, int Q, int Pld, int Qld)
{
    __shared__ float tile[32][33];
    const int qt = blockIdx.x * 32, pt = blockIdx.y * 32;
    const int tx = threadIdx.x, ty = threadIdx.y;  // (32,8)
    #pragma unroll
    for (int r = 0; r < 32; r += 8) {
        int p = pt + ty + r, q = qt + tx;
        tile[ty + r][tx] = (p < P && q < Q) ? src[(size_t)p * Q + q] : 0.f;
    }
    __syncthreads();
    #pragma unroll
    for (int r = 0; r < 32; r += 8) {
        int q = qt + ty + r, p = pt + tx;
        if (q < Qld && p < Pld) dst[(size_t)q * Pld + p] = f2bf(tile[tx][ty + r]);
    }
}

// ---------- GEMM: C[M,Nld] = A[M,K] x Bt[Nld,K]^T (bf16 in, fp32 acc) ----------
// m97 structure: 128x128 tile, BK=32, linear LDS, global_load_lds width=16.
// EPI 0: store bf16 (cols >= N zeroed)   EPI 1: store fp32   EPI 2: bf16(silu(acc)*other)
// Requires M%128==0, K%32==0. Bt must have Nld valid (readable) rows.
template<int EPI>
__global__ __launch_bounds__(256)
void gemm128(const unsigned short* __restrict__ A,
             const unsigned short* __restrict__ Bt,
             void* __restrict__ Cv,
             const unsigned short* __restrict__ other,
             int N, int Nld, int K, int gx)
{
    __shared__ unsigned short As[128 * 32];  // linear: row stride 32 (64B)
    __shared__ unsigned short Bs[128 * 32];
    const int tid  = threadIdx.x;
    const int bid  = xcd_swizzle(blockIdx.x, gridDim.x);
    const int n0   = (bid % gx) << 7;
    const int m0   = (bid / gx) << 7;
    const int lane = tid & 63;
    const int wave = tid >> 6;
    const int quad = lane >> 4;
    const int lr   = lane & 15;
    const int wm   = (wave >> 1) << 6;  // wave row offset within 128-tile
    const int wn   = (wave & 1) << 6;   // wave col offset

    const floatx4 zero = {0.f, 0.f, 0.f, 0.f};
    floatx4 acc[4][4];
    #pragma unroll
    for (int i = 0; i < 4; i++)
        #pragma unroll
        for (int j = 0; j < 4; j++) acc[i][j] = zero;

    // staging geometry: each wave stages 32 rows (2 x gl_lds of 16 rows) per matrix.
    // lane l covers row (l>>2), 16B chunk (l&3) within the 64B row.
    const int lrow = lane >> 2;          // 0..15
    const int lk8  = (lane & 3) << 3;    // 0,8,16,24 (shorts)

    unsigned short* lA0 = As + (wave * 32) * 32;       // wave-uniform LDS bases
    unsigned short* lA1 = lA0 + 16 * 32;
    unsigned short* lB0 = Bs + (wave * 32) * 32;
    unsigned short* lB1 = lB0 + 16 * 32;

    const unsigned short* gA0 = A + (size_t)(m0 + wave * 32 + lrow) * K + lk8;
    const unsigned short* gA1 = gA0 + (size_t)16 * K;
    int rb0 = n0 + wave * 32 + lrow;      if (rb0 >= Nld) rb0 = 0;  // clamp N tail
    int rb1 = n0 + wave * 32 + 16 + lrow; if (rb1 >= Nld) rb1 = 0;
    const unsigned short* gB0 = Bt + (size_t)rb0 * K + lk8;
    const unsigned short* gB1 = Bt + (size_t)rb1 * K + lk8;

    for (int k0 = 0; k0 < K; k0 += 32) {
        gl_lds16(gA0 + k0, lA0);
        gl_lds16(gA1 + k0, lA1);
        gl_lds16(gB0 + k0, lB0);
        gl_lds16(gB1 + k0, lB1);
        __syncthreads();   // compiler drains vmcnt here -> LDS tiles ready

        short8 af[4], bfr[4];
        #pragma unroll
        for (int mi = 0; mi < 4; mi++)
            af[mi] = *(const short8*)(As + (wm + mi * 16 + lr) * 32 + quad * 8);
        #pragma unroll
        for (int ni = 0; ni < 4; ni++)
            bfr[ni] = *(const short8*)(Bs + (wn + ni * 16 + lr) * 32 + quad * 8);
        #pragma unroll
        for (int mi = 0; mi < 4; mi++)
            #pragma unroll
            for (int ni = 0; ni < 4; ni++)
                acc[mi][ni] = __builtin_amdgcn_mfma_f32_16x16x32_bf16(
                    af[mi], bfr[ni], acc[mi][ni], 0, 0, 0);
        __syncthreads();   // all reads done before next stage overwrites
    }

    // epilogue: D row = quad*4 + i, col = lr (within each 16x16 tile)
    #pragma unroll
    for (int mi = 0; mi < 4; mi++) {
        const int growb = m0 + wm + mi * 16 + quad * 4;
        #pragma unroll
        for (int ni = 0; ni < 4; ni++) {
            const int col = n0 + wn + ni * 16 + lr;
            if (col < Nld) {
                #pragma unroll
                for (int i = 0; i < 4; i++) {
                    const size_t idx = (size_t)(growb + i) * Nld + col;
                    const float v = acc[mi][ni][i];
                    if (EPI == 0) {
                        ((unsigned short*)Cv)[idx] = (col < N) ? f2bf(v) : (unsigned short)0;
                    } else if (EPI == 1) {
                        ((float*)Cv)[idx] = v;
                    } else {
                        const float o = bf2f(other[idx]);
                        const float sg = v / (1.f + __expf(-v));  // silu
                        ((unsigned short*)Cv)[idx] = f2bf(sg * o);
                    }
                }
            }
        }
    }
}

// ---------- launch ----------
extern "C" void kernel_launch(void* const* d_in, const int* in_sizes, int n_in,
                              void* d_out, int out_size, void* d_ws, size_t ws_size,
                              hipStream_t stream)
{
    const float* x   = (const float*)d_in[0];
    const float* res = (const float*)d_in[1];
    const float* lnw = (const float*)d_in[2];
    const float* wgv = (const float*)d_in[3];  // [H,R]
    const float* wgu = (const float*)d_in[4];  // [R,I]
    const float* wuv = (const float*)d_in[5];  // [H,R]
    const float* wuu = (const float*)d_in[6];  // [R,I]
    const float* wdv = (const float*)d_in[7];  // [I,R]
    const float* wdu = (const float*)d_in[8];  // [R,H]

    const int H = in_sizes[2];
    const int T = (int)((long long)in_sizes[0] / H);  // B*S = 8192
    const int R = in_sizes[3] / H;                    // 1592
    const int I = in_sizes[4] / R;                    // 14336
    const int Rp = (R + 63) & ~63;                    // 1600: K%32==0, zero-padded

    // workspace layout (bf16 elements)
    unsigned short* p = (unsigned short*)d_ws;
    unsigned short* Wgv_t = p; p += (size_t)Rp * H;  // [Rp,H]  (pad rows zeroed)
    unsigned short* Wuv_t = p; p += (size_t)Rp * H;  // [Rp,H]
    unsigned short* Wgu_t = p; p += (size_t)I * Rp;  // [I,Rp]  (pad cols zeroed)
    unsigned short* Wuu_t = p; p += (size_t)I * Rp;  // [I,Rp]
    unsigned short* Wdv_t = p; p += (size_t)Rp * I;  // [Rp,I]  (pad rows zeroed)
    unsigned short* Wdu_t = p; p += (size_t)H * Rp;  // [H,Rp]  (pad cols zeroed)
    unsigned short* nbuf  = p; p += (size_t)T * H;   // [T,H]
    unsigned short* g1    = p; p += (size_t)T * Rp;  // [T,Rp]
    unsigned short* u1    = p; p += (size_t)T * Rp;  // [T,Rp]
    unsigned short* upm   = p; p += (size_t)T * I;   // [T,I] up, then m in-place
    unsigned short* d1    = nbuf;                    // [T,Rp] aliases nbuf (free after GEMM2)

    dim3 tb(32, 8);
    // dst [Qld,Pld], zero-padded beyond [Q,P]
    transpose_cast<<<dim3((Rp + 31) / 32, (H + 31) / 32), tb, 0, stream>>>(wgv, Wgv_t, H, R, H, Rp);
    transpose_cast<<<dim3((Rp + 31) / 32, (H + 31) / 32), tb, 0, stream>>>(wuv, Wuv_t, H, R, H, Rp);
    transpose_cast<<<dim3((I + 31) / 32, (Rp + 31) / 32), tb, 0, stream>>>(wgu, Wgu_t, R, I, Rp, I);
    transpose_cast<<<dim3((I + 31) / 32, (Rp + 31) / 32), tb, 0, stream>>>(wuu, Wuu_t, R, I, Rp, I);
    transpose_cast<<<dim3((Rp + 31) / 32, (I + 31) / 32), tb, 0, stream>>>(wdv, Wdv_t, I, R, I, Rp);
    transpose_cast<<<dim3((H + 31) / 32, (Rp + 31) / 32), tb, 0, stream>>>(wdu, Wdu_t, R, H, Rp, H);

    add_rmsnorm_kernel<<<T, 256, 0, stream>>>(x, res, lnw, nbuf, H, 1.0f / (float)H);

    const int gxR = (Rp + 127) / 128;  // 13
    const int gxI = (I + 127) / 128;   // 112
    const int gxH = (H + 127) / 128;   // 32
    const int gy  = T / 128;           // 64

    // g1 = n @ Wgv ; u1 = n @ Wuv
    gemm128<0><<<gxR * gy, 256, 0, stream>>>(nbuf, Wgv_t, g1, nullptr, R, Rp, H, gxR);
    gemm128<0><<<gxR * gy, 256, 0, stream>>>(nbuf, Wuv_t, u1, nullptr, R, Rp, H, gxR);
    // up = u1 @ Wuu
    gemm128<0><<<gxI * gy, 256, 0, stream>>>(u1, Wuu_t, upm, nullptr, I, I, Rp, gxI);
    // m = silu(g1 @ Wgu) * up   (in place over upm)
    gemm128<2><<<gxI * gy, 256, 0, stream>>>(g1, Wgu_t, upm, upm, I, I, Rp, gxI);
    // d1 = m @ Wdv
    gemm128<0><<<gxR * gy, 256, 0, stream>>>(upm, Wdv_t, d1, nullptr, R, Rp, I, gxR);
    // out = d1 @ Wdu  (fp32)
    gemm128<1><<<gxH * gy, 256, 0, stream>>>(d1, Wdu_t, d_out, nullptr, H, H, Rp, gxH);
}

// Round 3
// 2705.419 us; speedup vs baseline: 1.2473x; 1.1388x over previous
//
#include <hip/hip_runtime.h>
#include <cstdint>
#include <cstddef>

// ---------- types / helpers ----------
typedef __attribute__((ext_vector_type(8))) short short8;   // 8 x bf16 (4 VGPRs)
typedef __attribute__((ext_vector_type(4))) float floatx4;  // 4 x f32 accum

__device__ __forceinline__ float bf2f(unsigned short u) {
    union { float f; uint32_t i; } v; v.i = ((uint32_t)u) << 16; return v.f;
}
__device__ __forceinline__ unsigned short f2bf(float f) {
    union { float f; uint32_t i; } v; v.f = f;
    uint32_t r = v.i + 0x7FFFu + ((v.i >> 16) & 1u);  // round-nearest-even
    return (unsigned short)(r >> 16);
}

// async global->LDS, 16B per lane. LDS dest must be wave-uniform base;
// HW writes lane l's 16B at base + l*16.
__device__ __forceinline__ void gl_lds16(const unsigned short* g, unsigned short* l) {
    __builtin_amdgcn_global_load_lds(
        (const __attribute__((address_space(1))) unsigned int*)g,
        (__attribute__((address_space(3))) unsigned int*)l,
        16, 0, 0);
}

// bijective XCD-aware block swizzle (m204): contiguous chunk of ids per XCD
__device__ __forceinline__ int xcd_swizzle(int bid, int nwg) {
    const int nx = 8;
    const int q = nwg / nx, r = nwg % nx;
    const int xcd = bid % nx, local = bid / nx;
    return (xcd < r ? xcd * (q + 1) : r * (q + 1) + (xcd - r) * q) + local;
}

// ---------- fused add + RMSNorm -> bf16 ----------
__global__ __launch_bounds__(256)
void add_rmsnorm_kernel(const float* __restrict__ x, const float* __restrict__ res,
                        const float* __restrict__ w, unsigned short* __restrict__ out,
                        int H, float invH)
{
    const size_t row = blockIdx.x;
    const float4* xv = (const float4*)(x + row * (size_t)H);
    const float4* rv = (const float4*)(res + row * (size_t)H);
    const float4* wv = (const float4*)w;
    const int nvec = H >> 2;
    float4 h[8];
    float s = 0.f;
    int cnt = 0;
    for (int idx = threadIdx.x; idx < nvec; idx += 256) {
        float4 a = xv[idx], b = rv[idx];
        float4 hh = make_float4(a.x + b.x, a.y + b.y, a.z + b.z, a.w + b.w);
        h[cnt++] = hh;
        s += hh.x * hh.x + hh.y * hh.y + hh.z * hh.z + hh.w * hh.w;
    }
    __shared__ float red[256];
    red[threadIdx.x] = s;
    __syncthreads();
    for (int off = 128; off > 0; off >>= 1) {
        if (threadIdx.x < off) red[threadIdx.x] += red[threadIdx.x + off];
        __syncthreads();
    }
    const float scale = rsqrtf(red[0] * invH + 1e-5f);
    ushort4* ov = (ushort4*)(out + row * (size_t)H);
    cnt = 0;
    for (int idx = threadIdx.x; idx < nvec; idx += 256) {
        float4 hh = h[cnt++];
        float4 ww = wv[idx];
        ushort4 o;
        o.x = f2bf(hh.x * scale * ww.x);
        o.y = f2bf(hh.y * scale * ww.y);
        o.z = f2bf(hh.z * scale * ww.z);
        o.w = f2bf(hh.w * scale * ww.w);
        ov[idx] = o;
    }
}

// ---------- fp32 [P,Q] -> bf16 [Qld,Pld] transpose+cast, zero-padded ----------
__global__ __launch_bounds__(256)
void transpose_cast(const float* __restrict__ src, unsigned short* __restrict__ dst,
                    int P, int Q, int Pld, int Qld)
{
    __shared__ float tile[32][33];
    const int qt = blockIdx.x * 32, pt = blockIdx.y * 32;
    const int tx = threadIdx.x, ty = threadIdx.y;  // (32,8)
    #pragma unroll
    for (int r = 0; r < 32; r += 8) {
        int p = pt + ty + r, q = qt + tx;
        tile[ty + r][tx] = (p < P && q < Q) ? src[(size_t)p * Q + q] : 0.f;
    }
    __syncthreads();
    #pragma unroll
    for (int r = 0; r < 32; r += 8) {
        int q = qt + ty + r, p = pt + tx;
        if (q < Qld && p < Pld) dst[(size_t)q * Pld + p] = f2bf(tile[tx][ty + r]);
    }
}

// ---------- GEMM: C[M,Nld] = A[M,K](row stride lda) x Bt[Nld,K]^T ----------
// m97 structure + 2-phase prefetch (T3 minimum): double-buffered LDS,
// next tile's global_load_lds issued BEFORE current tile's ds_read+MFMA,
// so the barrier's vmcnt(0) drain lands after compute has covered latency.
// EPI 0: store bf16   EPI 1: store fp32   EPI 2: bf16(silu(acc)*other)
// Requires M%128==0, K%32==0. Bt must have Nld readable rows.
template<int EPI>
__global__ __launch_bounds__(256, 4)
void gemm128(const unsigned short* __restrict__ A,
             const unsigned short* __restrict__ Bt,
             void* __restrict__ Cv,
             const unsigned short* __restrict__ other,
             int Nld, int K, int lda, int gx)
{
    __shared__ unsigned short As0[128 * 32];  // linear: row stride 32 (64B)
    __shared__ unsigned short As1[128 * 32];
    __shared__ unsigned short Bs0[128 * 32];
    __shared__ unsigned short Bs1[128 * 32];
    const int tid  = threadIdx.x;
    const int bid  = xcd_swizzle(blockIdx.x, gridDim.x);
    const int n0   = (bid % gx) << 7;
    const int m0   = (bid / gx) << 7;
    const int lane = tid & 63;
    const int wave = tid >> 6;
    const int quad = lane >> 4;
    const int lr   = lane & 15;
    const int wm   = (wave >> 1) << 6;  // wave row offset within 128-tile
    const int wn   = (wave & 1) << 6;   // wave col offset

    const floatx4 zero = {0.f, 0.f, 0.f, 0.f};
    floatx4 acc[4][4];
    #pragma unroll
    for (int i = 0; i < 4; i++)
        #pragma unroll
        for (int j = 0; j < 4; j++) acc[i][j] = zero;

    // staging geometry: each wave stages 32 rows (2 x gl_lds of 16 rows) per matrix.
    // lane l covers row (l>>2), 16B chunk (l&3) within the 64B row.
    const int lrow = lane >> 2;          // 0..15
    const int lk8  = (lane & 3) << 3;    // 0,8,16,24 (shorts)
    const int woff = wave * 1024;        // wave*32 rows * 32 shorts

    const unsigned short* gA0 = A + (size_t)(m0 + wave * 32 + lrow) * lda + lk8;
    const unsigned short* gA1 = gA0 + (size_t)16 * lda;
    int rb0 = n0 + wave * 32 + lrow;      if (rb0 >= Nld) rb0 = 0;  // clamp N tail
    int rb1 = n0 + wave * 32 + 16 + lrow; if (rb1 >= Nld) rb1 = 0;
    const unsigned short* gB0 = Bt + (size_t)rb0 * K + lk8;
    const unsigned short* gB1 = Bt + (size_t)rb1 * K + lk8;

#define STAGE(ASL, BSL, kk)                          \
    {                                                \
        gl_lds16(gA0 + (kk), (ASL) + woff);          \
        gl_lds16(gA1 + (kk), (ASL) + woff + 512);    \
        gl_lds16(gB0 + (kk), (BSL) + woff);          \
        gl_lds16(gB1 + (kk), (BSL) + woff + 512);    \
    }

#define COMPUTE(ASL, BSL)                                                          \
    {                                                                              \
        short8 af[4], bfr[4];                                                      \
        _Pragma("unroll")                                                          \
        for (int mi = 0; mi < 4; mi++)                                             \
            af[mi] = *(const short8*)((ASL) + (wm + mi * 16 + lr) * 32 + quad * 8);\
        _Pragma("unroll")                                                          \
        for (int ni = 0; ni < 4; ni++)                                             \
            bfr[ni] = *(const short8*)((BSL) + (wn + ni * 16 + lr) * 32 + quad * 8);\
        _Pragma("unroll")                                                          \
        for (int mi = 0; mi < 4; mi++)                                             \
            _Pragma("unroll")                                                      \
            for (int ni = 0; ni < 4; ni++)                                         \
                acc[mi][ni] = __builtin_amdgcn_mfma_f32_16x16x32_bf16(             \
                    af[mi], bfr[ni], acc[mi][ni], 0, 0, 0);                        \
    }

    STAGE(As0, Bs0, 0);
    __syncthreads();
    int k0 = 0;
    for (;;) {
        int kn = k0 + 32;
        if (kn < K) STAGE(As1, Bs1, kn);   // prefetch ahead of compute
        COMPUTE(As0, Bs0);
        __syncthreads();                   // drains prefetch vmcnt after compute
        k0 = kn;
        if (k0 >= K) break;
        kn = k0 + 32;
        if (kn < K) STAGE(As0, Bs0, kn);
        COMPUTE(As1, Bs1);
        __syncthreads();
        k0 = kn;
        if (k0 >= K) break;
    }
#undef STAGE
#undef COMPUTE

    // epilogue: D row = quad*4 + i, col = lr (within each 16x16 tile)
    // padded cols are exact 0 (B pad rows zeroed), so no masking needed.
    #pragma unroll
    for (int mi = 0; mi < 4; mi++) {
        const int growb = m0 + wm + mi * 16 + quad * 4;
        #pragma unroll
        for (int ni = 0; ni < 4; ni++) {
            const int col = n0 + wn + ni * 16 + lr;
            if (col < Nld) {
                #pragma unroll
                for (int i = 0; i < 4; i++) {
                    const size_t idx = (size_t)(growb + i) * Nld + col;
                    const float v = acc[mi][ni][i];
                    if (EPI == 0) {
                        ((unsigned short*)Cv)[idx] = f2bf(v);
                    } else if (EPI == 1) {
                        ((float*)Cv)[idx] = v;
                    } else {
                        const float o = bf2f(other[idx]);
                        const float sg = v / (1.f + __expf(-v));  // silu
                        ((unsigned short*)Cv)[idx] = f2bf(sg * o);
                    }
                }
            }
        }
    }
}

// ---------- launch ----------
extern "C" void kernel_launch(void* const* d_in, const int* in_sizes, int n_in,
                              void* d_out, int out_size, void* d_ws, size_t ws_size,
                              hipStream_t stream)
{
    const float* x   = (const float*)d_in[0];
    const float* res = (const float*)d_in[1];
    const float* lnw = (const float*)d_in[2];
    const float* wgv = (const float*)d_in[3];  // [H,R]
    const float* wgu = (const float*)d_in[4];  // [R,I]
    const float* wuv = (const float*)d_in[5];  // [H,R]
    const float* wuu = (const float*)d_in[6];  // [R,I]
    const float* wdv = (const float*)d_in[7];  // [I,R]
    const float* wdu = (const float*)d_in[8];  // [R,H]

    const int H = in_sizes[2];
    const int T = (int)((long long)in_sizes[0] / H);  // B*S = 8192
    const int R = in_sizes[3] / H;                    // 1592
    const int I = in_sizes[4] / R;                    // 14336
    const int Rp = (R + 63) & ~63;                    // 1600: K%32==0, zero-padded
    const int R2 = 2 * Rp;                            // 3200 (gate||up fused width)

    // workspace layout (bf16 elements)
    unsigned short* p = (unsigned short*)d_ws;
    unsigned short* Wgv_t = p; p += (size_t)Rp * H;  // [Rp,H]  (pad rows zeroed)
    unsigned short* Wuv_t = p; p += (size_t)Rp * H;  // [Rp,H]  adjacent => [2Rp,H]
    unsigned short* Wgu_t = p; p += (size_t)I * Rp;  // [I,Rp]  (pad cols zeroed)
    unsigned short* Wuu_t = p; p += (size_t)I * Rp;  // [I,Rp]
    unsigned short* Wdv_t = p; p += (size_t)Rp * I;  // [Rp,I]  (pad rows zeroed)
    unsigned short* Wdu_t = p; p += (size_t)H * Rp;  // [H,Rp]  (pad cols zeroed)
    unsigned short* nbuf  = p; p += (size_t)T * H;   // [T,H]
    unsigned short* gu1   = p; p += (size_t)T * R2;  // [T,2Rp]: cols [0,Rp)=gate, [Rp,2Rp)=up
    unsigned short* upm   = p; p += (size_t)T * I;   // [T,I] up, then m in-place
    unsigned short* d1    = nbuf;                    // [T,Rp] aliases nbuf (free after GEMM1)

    dim3 tb(32, 8);
    // dst [Qld,Pld], zero-padded beyond [Q,P]
    transpose_cast<<<dim3((Rp + 31) / 32, (H + 31) / 32), tb, 0, stream>>>(wgv, Wgv_t, H, R, H, Rp);
    transpose_cast<<<dim3((Rp + 31) / 32, (H + 31) / 32), tb, 0, stream>>>(wuv, Wuv_t, H, R, H, Rp);
    transpose_cast<<<dim3((I + 31) / 32, (Rp + 31) / 32), tb, 0, stream>>>(wgu, Wgu_t, R, I, Rp, I);
    transpose_cast<<<dim3((I + 31) / 32, (Rp + 31) / 32), tb, 0, stream>>>(wuu, Wuu_t, R, I, Rp, I);
    transpose_cast<<<dim3((Rp + 31) / 32, (I + 31) / 32), tb, 0, stream>>>(wdv, Wdv_t, I, R, I, Rp);
    transpose_cast<<<dim3((H + 31) / 32, (Rp + 31) / 32), tb, 0, stream>>>(wdu, Wdu_t, R, H, Rp, H);

    add_rmsnorm_kernel<<<T, 256, 0, stream>>>(x, res, lnw, nbuf, H, 1.0f / (float)H);

    const int gx12 = R2 / 128;         // 25
    const int gxR  = (Rp + 127) / 128; // 13
    const int gxI  = (I + 127) / 128;  // 112
    const int gxH  = (H + 127) / 128;  // 32
    const int gy   = T / 128;          // 64

    // gu1 = n @ [Wgv | Wuv]   (fused: one pass over n)
    gemm128<0><<<gx12 * gy, 256, 0, stream>>>(nbuf, Wgv_t, gu1, nullptr, R2, H, H, gx12);
    // up = u1 @ Wuu           (u1 = strided view of gu1)
    gemm128<0><<<gxI * gy, 256, 0, stream>>>(gu1 + Rp, Wuu_t, upm, nullptr, I, Rp, R2, gxI);
    // m = silu(g1 @ Wgu) * up (in place over upm)
    gemm128<2><<<gxI * gy, 256, 0, stream>>>(gu1, Wgu_t, upm, upm, I, Rp, R2, gxI);
    // d1 = m @ Wdv
    gemm128<0><<<gxR * gy, 256, 0, stream>>>(upm, Wdv_t, d1, nullptr, Rp, I, I, gxR);
    // out = d1 @ Wdu  (fp32)
    gemm128<1><<<gxH * gy, 256, 0, stream>>>(d1, Wdu_t, d_out, nullptr, H, Rp, Rp, gxH);
}